// Round 10
// baseline (11625.672 us; speedup 1.0000x reference)
//
#include <hip/hip_runtime.h>
#include <hip/hip_bf16.h>

#define TT 512
#define BB 128
#define II 256
#define HH 512
#define OO 256

#define PAIRS 32
#define ROWS  4
#define RING  8
#define HP    520   // padded LDS row stride (bf16 elems) for HH
#define IP    264   // padded LDS row stride for II

#define PRED_SZ (TT*OO)

typedef __attribute__((ext_vector_type(8))) short bf16x8;
typedef __attribute__((ext_vector_type(4))) float f32x4;
typedef __attribute__((ext_vector_type(4))) int   i32x4;
typedef __attribute__((ext_vector_type(2))) int   i32x2;
typedef __attribute__((ext_vector_type(2))) unsigned u32x2;

// workspace layout (bytes)
#define WS_F1   0                                  // flag1[32 pairs][32] int
#define WS_F2   4096                               // flag2[32 pairs][32] int
#define WS_RING 8192                               // bf16 [PAIRS][RING][ROWS][HH] = 1 MB
#define WS_SAVE (8192 + PAIRS*RING*ROWS*HH*2)      // [TT][HH] f32 = 1 MB
#define WS_ZERO 8192                               // zero flags only

__device__ __forceinline__ ushort f2bf(float f) {
  union { float f; unsigned u; } v; v.f = f;
  unsigned u = v.u;
  return (ushort)((u + 0x7FFFu + ((u >> 16) & 1u)) >> 16);   // RNE
}

__device__ __forceinline__ float fast_tanh(float x) {
  float cx = fminf(fmaxf(x, -30.f), 30.f);
  float t  = __builtin_amdgcn_exp2f(cx * 2.885390081777927f);  // e^(2x)
  return (t - 1.f) * __builtin_amdgcn_rcpf(t + 1.f);
}

// ---- IF$-coherent primitives (round-2/6 proven: sc0 sc1 both ways) ----
__device__ __forceinline__ i32x4 ld16(const ushort* p) {
  i32x4 r;
  asm volatile("global_load_dwordx4 %0, %1, off sc0 sc1" : "=v"(r) : "v"(p) : "memory");
  return r;
}
__device__ __forceinline__ void st8(ushort* p, i32x2 v) {
  asm volatile("global_store_dwordx2 %0, %1, off sc0 sc1" :: "v"(p), "v"(v) : "memory");
}
__device__ __forceinline__ void st_flag(int* p, int v) {
  asm volatile("global_store_dword %0, %1, off sc0 sc1" :: "v"(p), "v"(v) : "memory");
}
__device__ __forceinline__ int ld_flag(const int* p) {
  int r;
  asm volatile("global_load_dword %0, %1, off sc0 sc1\n\ts_waitcnt vmcnt(0)"
               : "=v"(r) : "v"(p) : "memory");
  return r;
}
__device__ __forceinline__ void ldf_issue(const int* p, int& r) {
  asm volatile("global_load_dword %0, %1, off sc0 sc1" : "=v"(r) : "v"(p) : "memory");
}
#define WAIT_VM(N) asm volatile("s_waitcnt vmcnt(" #N ")" ::: "memory")
#define SBAR() __builtin_amdgcn_sched_barrier(0)

__device__ __forceinline__ f32x4 MFMA(bf16x8 a, bf16x8 b, f32x4 c) {
  return __builtin_amdgcn_mfma_f32_16x16x32_bf16(a, b, c, 0, 0, 0);
}

__global__ __launch_bounds__(1024) void rnn_scan_kernel(
    const float* __restrict__ x,
    const float* __restrict__ Wih0, const float* __restrict__ bih0,
    const float* __restrict__ Whh0, const float* __restrict__ bhh0,
    const float* __restrict__ Wih1, const float* __restrict__ bih1,
    const float* __restrict__ Whh1, const float* __restrict__ bhh1,
    float* __restrict__ out, char* __restrict__ ws)
{
  __shared__ ushort bufA[2][ROWS][HP];  // L0: h1 ping-pong | L1: staged h1
  __shared__ ushort bufB[2][ROWS][HP];  // L1: h2 ping-pong | L0: unused
  __shared__ ushort xst[2][ROWS][IP];   // L0: staged x (bf16)
  __shared__ int arr;

  int*    flag1  = (int*)(ws + WS_F1);
  int*    flag2  = (int*)(ws + WS_F2);
  ushort* ring   = (ushort*)(ws + WS_RING);
  float*  h2save = (float*)(ws + WS_SAVE);

  const int  bid  = blockIdx.x;
  const int  pair = bid & (PAIRS-1);
  const bool isL1 = bid >= PAIRS;
  const int  tid  = threadIdx.x;
  const int  w    = tid >> 6;
  const int  lane = tid & 63;
  const int  kq   = lane >> 4;
  const int  c    = lane & 15;
  const int  rl   = c & 3;               // duplicated batch-row index
  const int  cb0  = 32*w;                // wave's column base
  const int  cw   = kq*4;                // lane col offset within a 16-col tile
  ushort* ringp = ring + (size_t)pair*RING*ROWS*HH;
  int* f1p = flag1 + pair*32;
  int* f2p = flag2 + pair*32;

  // zero the "previous" LDS buffers (h[-1] = 0, h[-2] = 0)
  {
    ushort* zA = &bufA[1][0][0];
    ushort* zB = &bufB[1][0][0];
    for (int i = tid; i < ROWS*HP; i += 1024) { zA[i] = 0; zB[i] = 0; }
    if (tid == 0) arr = 0;
  }

  // fragment loader: W fp32 row-major [N][ldk] -> bf16x8 first-operand frag
  auto ldfrag = [&](const float* W, int ldk, int n, int k) -> bf16x8 {
    const float* p = W + (size_t)n*ldk + k;
    const f32x4 v0 = *(const f32x4*)p;
    const f32x4 v1 = *(const f32x4*)(p+4);
    bf16x8 r;
    #pragma unroll
    for (int j = 0; j < 4; ++j) { r[j] = (short)f2bf(v0[j]); r[j+4] = (short)f2bf(v1[j]); }
    return r;
  };

  if (!isL1) {
    // ================= LAYER 0 block: h1[p] = tanh(x[p] Wih0^T + h1[p-1] Whh0^T + b) =================
    bf16x8 whh[2][16], wih[2][8];
    f32x4 bias[2];
    #pragma unroll
    for (int t = 0; t < 2; ++t) {
      #pragma unroll
      for (int kk = 0; kk < 16; ++kk) whh[t][kk] = ldfrag(Whh0, HH, cb0 + 16*t + c, 32*kk + kq*8);
      #pragma unroll
      for (int kk = 0; kk < 8;  ++kk) wih[t][kk] = ldfrag(Wih0, II, cb0 + 16*t + c, 32*kk + kq*8);
      const int nb = cb0 + 16*t + cw;
      bias[t] = (f32x4){ bih0[nb]+bhh0[nb], bih0[nb+1]+bhh0[nb+1],
                         bih0[nb+2]+bhh0[nb+2], bih0[nb+3]+bhh0[nb+3] };
    }
    // prologue: stage x[0] (wave 14)
    if (w == 14) {
      const float* xp = x + (size_t)pair*ROWS*II;   // 1024 contiguous floats
      #pragma unroll
      for (int i = 0; i < 4; ++i) {
        const f32x4 v = *(const f32x4*)(xp + i*256 + lane*4);
        u32x2 d;
        d.x = (unsigned)f2bf(v[0]) | ((unsigned)f2bf(v[1]) << 16);
        d.y = (unsigned)f2bf(v[2]) | ((unsigned)f2bf(v[3]) << 16);
        *(u32x2*)&xst[0][i][lane*4] = d;
      }
    }
    __syncthreads();

    int vf2 = 0;
    for (int p = 0; p < TT; ++p) {
      // early issues: ring-reuse gate flag + next-step x loads
      int f2v = vf2;
      if (p >= RING) ldf_issue(f2p, f2v);
      f32x4 xv[4];
      const bool stgx = (w == 14 && p+1 < TT);
      if (stgx) {
        const float* xp = x + ((size_t)(p+1)*BB + pair*ROWS)*II;
        #pragma unroll
        for (int i = 0; i < 4; ++i) xv[i] = *(const f32x4*)(xp + i*256 + lane*4);
      }
      // MFMA phase
      f32x4 a0 = {0.f,0.f,0.f,0.f}, a1 = {0.f,0.f,0.f,0.f};
      {
        const ushort* hb = &bufA[(p-1)&1][rl][0];
        #pragma unroll
        for (int kk = 0; kk < 16; ++kk) {
          const bf16x8 hf = *(const bf16x8*)&hb[32*kk + kq*8];
          a0 = MFMA(whh[0][kk], hf, a0);
          a1 = MFMA(whh[1][kk], hf, a1);
        }
        const ushort* xb = &xst[p&1][rl][0];
        #pragma unroll
        for (int kk = 0; kk < 8; ++kk) {
          const bf16x8 xf = *(const bf16x8*)&xb[32*kk + kq*8];
          a0 = MFMA(wih[0][kk], xf, a0);
          a1 = MFMA(wih[1][kk], xf, a1);
        }
      }
      f32x4 o0, o1;
      #pragma unroll
      for (int j = 0; j < 4; ++j) {
        o0[j] = fast_tanh(a0[j] + bias[0][j]);
        o1[j] = fast_tanh(a1[j] + bias[1][j]);
      }
      // single sync point: drains prev-step ring stores + f2 load + x loads
      WAIT_VM(0); SBAR();
      if (lane == 0 && p >= 1) {
        int old = atomicAdd(&arr, 1);
        if (old == 16*p - 1) st_flag(f1p, p);       // h1[p-1] visible
      }
      if (p >= RING) {
        if (!__all(f2v >= p - RING)) {
          do { f2v = ld_flag(f2p); } while (!__all(f2v >= p - RING));
        }
        vf2 = f2v;
      }
      // writes: LDS ping-pong + global ring (+ h_final at the end)
      u32x2 d0, d1;
      d0.x = (unsigned)f2bf(o0[0]) | ((unsigned)f2bf(o0[1]) << 16);
      d0.y = (unsigned)f2bf(o0[2]) | ((unsigned)f2bf(o0[3]) << 16);
      d1.x = (unsigned)f2bf(o1[0]) | ((unsigned)f2bf(o1[1]) << 16);
      d1.y = (unsigned)f2bf(o1[2]) | ((unsigned)f2bf(o1[3]) << 16);
      if (c < ROWS) {
        *(u32x2*)&bufA[p&1][c][cb0 + cw]      = d0;
        *(u32x2*)&bufA[p&1][c][cb0 + 16 + cw] = d1;
        ushort* rp = ringp + ((size_t)(p&(RING-1))*ROWS + c)*HH + cb0 + cw;
        st8(rp,      (i32x2){(int)d0.x, (int)d0.y});
        st8(rp + 16, (i32x2){(int)d1.x, (int)d1.y});
        if (p == TT-1) {
          float* op = out + PRED_SZ + (size_t)(pair*ROWS + c)*HH + cb0 + cw;
          *(f32x4*)op        = o0;
          *(f32x4*)(op + 16) = o1;
        }
      }
      if (stgx) {
        #pragma unroll
        for (int i = 0; i < 4; ++i) {
          u32x2 d;
          d.x = (unsigned)f2bf(xv[i][0]) | ((unsigned)f2bf(xv[i][1]) << 16);
          d.y = (unsigned)f2bf(xv[i][2]) | ((unsigned)f2bf(xv[i][3]) << 16);
          *(u32x2*)&xst[(p+1)&1][i][lane*4] = d;
        }
      }
      __syncthreads();
    }
    // final flag: h1[TT-1]
    WAIT_VM(0);
    if (lane == 0) {
      int old = atomicAdd(&arr, 1);
      if (old == 16*TT - 1) st_flag(f1p, TT);
    }
  } else {
    // ================= LAYER 1 block: h2[p-1] = tanh(h1[p-1] Wih1^T + h2[p-2] Whh1^T + b) =================
    bf16x8 wih[2][16], whh[2][16];
    f32x4 bias[2];
    #pragma unroll
    for (int t = 0; t < 2; ++t) {
      #pragma unroll
      for (int kk = 0; kk < 16; ++kk) {
        wih[t][kk] = ldfrag(Wih1, HH, cb0 + 16*t + c, 32*kk + kq*8);
        whh[t][kk] = ldfrag(Whh1, HH, cb0 + 16*t + c, 32*kk + kq*8);
      }
      const int nb = cb0 + 16*t + cw;
      bias[t] = (f32x4){ bih1[nb]+bhh1[nb], bih1[nb+1]+bhh1[nb+1],
                         bih1[nb+2]+bhh1[nb+2], bih1[nb+3]+bhh1[nb+3] };
    }
    __syncthreads();

    int f1v = 0;
    // prologue: stage h1[0] (wave 15)
    if (w == 15) {
      do { f1v = ld_flag(f1p); } while (f1v < 1);
      const ushort* rp = ringp + lane*8;            // slot 0
      i32x4 rv[4];
      #pragma unroll
      for (int i = 0; i < 4; ++i) rv[i] = ld16(rp + i*HH);
      WAIT_VM(0); SBAR();
      #pragma unroll
      for (int i = 0; i < 4; ++i) *(i32x4*)&bufA[0][i][lane*8] = rv[i];
      st_flag(f2p, 0);
    }
    __syncthreads();

    for (int p = 1; p <= TT; ++p) {
      // wave15: poll+load next h1 early (latency hidden under MFMAs)
      i32x4 rv[4];
      const bool stg = (w == 15 && p < TT);
      if (stg) {
        if (f1v < p+1) { do { f1v = ld_flag(f1p); } while (f1v < p+1); }
        const ushort* rp = ringp + (size_t)(p&(RING-1))*ROWS*HH + lane*8;
        #pragma unroll
        for (int i = 0; i < 4; ++i) rv[i] = ld16(rp + i*HH);
      }
      // MFMA phase
      f32x4 a0 = {0.f,0.f,0.f,0.f}, a1 = {0.f,0.f,0.f,0.f};
      {
        const ushort* h1b = &bufA[(p-1)&1][rl][0];
        const ushort* h2b = &bufB[p&1][rl][0];      // (p-2)&1 == p&1
        #pragma unroll
        for (int kk = 0; kk < 16; ++kk) {
          const bf16x8 f1f = *(const bf16x8*)&h1b[32*kk + kq*8];
          const bf16x8 f2f = *(const bf16x8*)&h2b[32*kk + kq*8];
          a0 = MFMA(wih[0][kk], f1f, a0);
          a1 = MFMA(wih[1][kk], f1f, a1);
          a0 = MFMA(whh[0][kk], f2f, a0);
          a1 = MFMA(whh[1][kk], f2f, a1);
        }
      }
      f32x4 o0, o1;
      #pragma unroll
      for (int j = 0; j < 4; ++j) {
        o0[j] = fast_tanh(a0[j] + bias[0][j]);
        o1[j] = fast_tanh(a1[j] + bias[1][j]);
      }
      if (stg) {
        WAIT_VM(0); SBAR();
        #pragma unroll
        for (int i = 0; i < 4; ++i) *(i32x4*)&bufA[p&1][i][lane*8] = rv[i];
        st_flag(f2p, p);                             // h1[p] consumed from ring
      }
      // write h2[p-1] into LDS ping-pong + side outputs
      if (c < ROWS) {
        u32x2 d0, d1;
        d0.x = (unsigned)f2bf(o0[0]) | ((unsigned)f2bf(o0[1]) << 16);
        d0.y = (unsigned)f2bf(o0[2]) | ((unsigned)f2bf(o0[3]) << 16);
        d1.x = (unsigned)f2bf(o1[0]) | ((unsigned)f2bf(o1[1]) << 16);
        d1.y = (unsigned)f2bf(o1[2]) | ((unsigned)f2bf(o1[3]) << 16);
        *(u32x2*)&bufB[(p-1)&1][c][cb0 + cw]      = d0;
        *(u32x2*)&bufB[(p-1)&1][c][cb0 + 16 + cw] = d1;
        if (pair == PAIRS-1 && c == ROWS-1) {        // global batch row 127
          float* sp = h2save + (size_t)(p-1)*HH + cb0 + cw;
          *(f32x4*)sp        = o0;
          *(f32x4*)(sp + 16) = o1;
        }
        if (p == TT) {
          float* op = out + PRED_SZ + BB*HH + (size_t)(pair*ROWS + c)*HH + cb0 + cw;
          *(f32x4*)op        = o0;
          *(f32x4*)(op + 16) = o1;
        }
      }
      __syncthreads();
    }
  }
}

__global__ __launch_bounds__(256) void rnn_pred_kernel(
    const float* __restrict__ Wfc, const float* __restrict__ bfc,
    const float* __restrict__ h2save, float* __restrict__ out)
{
  __shared__ float hs[HH];
  const int t = blockIdx.x;
  for (int i = threadIdx.x; i < HH; i += 256) hs[i] = h2save[(size_t)t*HH + i];
  __syncthreads();
  const int o = threadIdx.x;
  const f32x4* wr = (const f32x4*)(Wfc + (size_t)o*HH);
  f32x4 s = {0.f,0.f,0.f,0.f};
  #pragma unroll 8
  for (int k = 0; k < HH/4; ++k) {
    const f32x4 wv = wr[k];
    const f32x4 hv = *(const f32x4*)&hs[4*k];
    s += wv * hv;
  }
  out[(size_t)t*OO + o] = bfc[o] + s[0] + s[1] + s[2] + s[3];
}

extern "C" void kernel_launch(void* const* d_in, const int* in_sizes, int n_in,
                              void* d_out, int out_size, void* d_ws, size_t ws_size,
                              hipStream_t stream) {
  const float* x    = (const float*)d_in[0];
  const float* Wih0 = (const float*)d_in[1];
  const float* bih0 = (const float*)d_in[2];
  const float* Whh0 = (const float*)d_in[3];
  const float* bhh0 = (const float*)d_in[4];
  const float* Wih1 = (const float*)d_in[5];
  const float* bih1 = (const float*)d_in[6];
  const float* Whh1 = (const float*)d_in[7];
  const float* bhh1 = (const float*)d_in[8];
  const float* Wfc  = (const float*)d_in[9];
  const float* bfc  = (const float*)d_in[10];
  float* out = (float*)d_out;
  char*  ws  = (char*)d_ws;

  // zero the flag arrays every launch (monotone counters start at 0)
  hipMemsetAsync(ws, 0, WS_ZERO, stream);

  rnn_scan_kernel<<<2*PAIRS, 1024, 0, stream>>>(x, Wih0, bih0, Whh0, bhh0,
                                                Wih1, bih1, Whh1, bhh1, out, ws);
  rnn_pred_kernel<<<TT, 256, 0, stream>>>(Wfc, bfc, (const float*)(ws + WS_SAVE), out);
}